// Round 7
// baseline (382.869 us; speedup 1.0000x reference)
//
#include <hip/hip_runtime.h>
#include <hip/hip_bf16.h>
#include <math.h>

#define NDIM 4096
#define CDIM 256
#define KD   32
#define SCALE 0.17677669529663687f   // 1/sqrt(32)
// ALPHA = SCALE * log2(e): folded into Wf so scores are base-2 exponents
#define ALPHA (0.17677669529663687f * 1.44269504088896341f)
#define SHIFT2 11.541560327111707f   // 8 * log2(e)

typedef __attribute__((ext_vector_type(8))) short short8;  // 8 bf16 = 4 VGPRs
typedef __attribute__((ext_vector_type(4))) float f32x4;
typedef unsigned short u16;
typedef unsigned int u32;

__device__ __forceinline__ u32 f2bf(float x) {  // fp32 -> bf16 bits, RNE
  union { float f; u32 u; } v; v.f = x;
  return (v.u + 0x7FFFu + ((v.u >> 16) & 1u)) >> 16;
}

__device__ __forceinline__ u32 pack_bf16x2(float a, float b) {
  __hip_bfloat162 h2 = __float22bfloat162_rn(make_float2(a, b));
  u32 r;
  __builtin_memcpy(&r, &h2, 4);
  return r;
}

#define MFMA16(a, b, c) __builtin_amdgcn_mfma_f32_16x16x32_bf16((a), (b), (c), 0, 0, 0)

// ---------------------------------------------------------------------------
// cast all weights fp32 -> bf16. f-weights pre-scaled by ALPHA so that
// score MFMAs directly produce base-2 exponents (exp2 = native v_exp_f32).
// ---------------------------------------------------------------------------
__global__ void cast_all_kernel(const float* __restrict__ h1w,
                                const float* __restrict__ h2w,
                                const float* __restrict__ fw,
                                const float* __restrict__ gw,
                                u16* __restrict__ dst) {
  int i = blockIdx.x * 256 + threadIdx.x;
  float v;
  if (i < 65536) v = h1w[i];
  else if (i < 131072) v = h2w[i - 65536];
  else if (i < 139264) v = fw[i - 131072] * ALPHA;
  else v = gw[i - 139264];
  dst[i] = (u16)f2bf(v);
}

// ---------------------------------------------------------------------------
// x[b][C][n] fp32 -> xT[bb][n][C] bf16
// ---------------------------------------------------------------------------
__global__ __launch_bounds__(256) void transpose_cast_kernel(
    const float* __restrict__ x1, const float* __restrict__ x2,
    u16* __restrict__ xt) {
  __shared__ float ts[64][68];
  const int t = threadIdx.x;
  const int ntile = blockIdx.x * 64, Ctile = blockIdx.y * 64, z = blockIdx.z;
  const float* xb = ((z >> 2) ? x2 : x1) + (size_t)(z & 3) * CDIM * NDIM;
  u16* xtb = xt + (size_t)z * NDIM * CDIM;
  const int r = t >> 4, c4 = (t & 15) * 4;
#pragma unroll
  for (int i = 0; i < 4; i++) {
    float4 v = *(const float4*)&xb[(size_t)(Ctile + r + i * 16) * NDIM + ntile + c4];
    *(float4*)&ts[r + i * 16][c4] = v;
  }
  __syncthreads();
  const int n = t >> 2, Cg = (t & 3) * 16;
  u32 pk[8];
#pragma unroll
  for (int j = 0; j < 8; j++) {
    u32 lo = f2bf(ts[Cg + 2 * j][n]);
    u32 hi = f2bf(ts[Cg + 2 * j + 1][n]);
    pk[j] = lo | (hi << 16);
  }
  uint4* dst = (uint4*)&xtb[(size_t)(ntile + n) * CDIM + Ctile + Cg];
  dst[0] = make_uint4(pk[0], pk[1], pk[2], pk[3]);
  dst[1] = make_uint4(pk[4], pk[5], pk[6], pk[7]);
}

// ---------------------------------------------------------------------------
// conv f+g fused via MFMA. block 256 (4 waves), tile 32o x 64n, grid (64, 8)
// f-bias scaled by ALPHA to match pre-scaled Wf.
// ---------------------------------------------------------------------------
__global__ __launch_bounds__(256) void conv_fg_kernel(
    const u16* __restrict__ Wf, const float* __restrict__ fbias,
    const u16* __restrict__ Wg, const float* __restrict__ gbias,
    const u16* __restrict__ xt, u16* __restrict__ ftT, u16* __restrict__ gtT) {
  const int t = threadIdx.x, w = t >> 6, l = t & 63, li = l & 15, q = l >> 4;
  const int ntile = blockIdx.x * 64, bb = blockIdx.y;
  const u16* xtb = xt + (size_t)bb * NDIM * CDIM;
  f32x4 zero4 = {0.f, 0.f, 0.f, 0.f};
  f32x4 acc[2][2];
  for (int i = 0; i < 2; i++) for (int j = 0; j < 2; j++) acc[i][j] = zero4;
  const int nrow = ntile + w * 16 + li;

  for (int k0 = 0; k0 < CDIM; k0 += 32) {
    short8 bx = *(const short8*)&xtb[(size_t)nrow * CDIM + k0 + q * 8];
    short8 af0 = *(const short8*)&Wf[(size_t)(li) * CDIM + k0 + q * 8];
    short8 af1 = *(const short8*)&Wf[(size_t)(16 + li) * CDIM + k0 + q * 8];
    short8 ag0 = *(const short8*)&Wg[(size_t)(li) * CDIM + k0 + q * 8];
    short8 ag1 = *(const short8*)&Wg[(size_t)(16 + li) * CDIM + k0 + q * 8];
    acc[0][0] = MFMA16(af0, bx, acc[0][0]);
    acc[0][1] = MFMA16(af1, bx, acc[0][1]);
    acc[1][0] = MFMA16(ag0, bx, acc[1][0]);
    acc[1][1] = MFMA16(ag1, bx, acc[1][1]);
  }
  u16* outs[2] = {ftT + (size_t)bb * NDIM * KD, gtT + (size_t)bb * NDIM * KD};
  const float* biases[2] = {fbias, gbias};
  const float bscale[2] = {ALPHA, 1.0f};
#pragma unroll
  for (int fg = 0; fg < 2; fg++) {
#pragma unroll
    for (int os = 0; os < 2; os++) {
      float b0 = biases[fg][os * 16 + q * 4 + 0] * bscale[fg];
      float b1 = biases[fg][os * 16 + q * 4 + 1] * bscale[fg];
      float b2 = biases[fg][os * 16 + q * 4 + 2] * bscale[fg];
      float b3 = biases[fg][os * 16 + q * 4 + 3] * bscale[fg];
      u32 p0 = f2bf(acc[fg][os][0] + b0) | (f2bf(acc[fg][os][1] + b1) << 16);
      u32 p1 = f2bf(acc[fg][os][2] + b2) | (f2bf(acc[fg][os][3] + b3) << 16);
      *(uint2*)&outs[fg][(size_t)nrow * KD + os * 16 + q * 4] = make_uint2(p0, p1);
    }
  }
}

// ---------------------------------------------------------------------------
// stats (base-2): L2[n] = SHIFT2 + log2(sum_m 2^(S2[n,m]-SHIFT2)),
// where S2 = s*SCALE*log2e (ft pre-scaled). L2 = L*log2e.
// ---------------------------------------------------------------------------
__global__ __launch_bounds__(256) void stats_kernel(
    const u16* __restrict__ ft, const u16* __restrict__ gt,
    float* __restrict__ L) {
  __shared__ float zred[32][64];
  const int t = threadIdx.x, w = t >> 6, l = t & 63, li = l & 15, q = l >> 4;
  const int n0 = blockIdx.x * 32;
  const int bb = blockIdx.z * 4 + blockIdx.y;
  const u16* ftb = ft + (size_t)bb * NDIM * KD;
  const u16* gtb = gt + (size_t)bb * NDIM * KD;
  f32x4 zero4 = {0.f, 0.f, 0.f, 0.f};

  short8 a0 = *(const short8*)&ftb[(size_t)(n0 + li) * KD + q * 8];
  short8 a1 = *(const short8*)&ftb[(size_t)(n0 + 16 + li) * KD + q * 8];
  f32x4 z0 = zero4, z1 = zero4;

#pragma unroll 2
  for (int it = 0; it < 64; it++) {
    int m = (it * 4 + w) * 16;
    short8 bf = *(const short8*)&gtb[(size_t)(m + li) * KD + q * 8];
    f32x4 S0 = MFMA16(a0, bf, zero4);
    f32x4 S1 = MFMA16(a1, bf, zero4);
#pragma unroll
    for (int reg = 0; reg < 4; reg++) {
      z0[reg] += exp2f(S0[reg] - SHIFT2);
      z1[reg] += exp2f(S1[reg] - SHIFT2);
    }
  }
#pragma unroll
  for (int reg = 0; reg < 4; reg++) {
    zred[q * 4 + reg][w * 16 + li] = z0[reg];
    zred[16 + q * 4 + reg][w * 16 + li] = z1[reg];
  }
  __syncthreads();
  const int r = t >> 3, i8 = t & 7;
  float4 s1 = *(const float4*)&zred[r][i8 * 8];
  float4 s2 = *(const float4*)&zred[r][i8 * 8 + 4];
  float sum = s1.x + s1.y + s1.z + s1.w + s2.x + s2.y + s2.z + s2.w;
  sum += __shfl_xor(sum, 1, 8);
  sum += __shfl_xor(sum, 2, 8);
  sum += __shfl_xor(sum, 4, 8);
  if (i8 == 0) L[(size_t)bb * NDIM + n0 + r] = SHIFT2 + __log2f(sum);
}

// ---------------------------------------------------------------------------
// conv h (both branches) via MFMA, with 2^{-L2[n]} folded into the output:
// h'[c][n] = (W @ x + bias)[c][n] * 2^{-L2[n]}.
// ---------------------------------------------------------------------------
__global__ __launch_bounds__(256) void conv_h_kernel(
    const u16* __restrict__ Wall, const float* __restrict__ b1,
    const float* __restrict__ b2, const u16* __restrict__ xt,
    const float* __restrict__ L, u16* __restrict__ outH) {
  const int t = threadIdx.x, w = t >> 6, l = t & 63, li = l & 15, q = l >> 4;
  const int ntile = blockIdx.x * 64;
  const int o0 = blockIdx.y * 64 + w * 16;
  const int bb = blockIdx.z, branch = bb >> 2;
  const u16* W = Wall + (size_t)branch * CDIM * CDIM;
  const float* bias = branch ? b2 : b1;
  const u16* xtb = xt + (size_t)bb * NDIM * CDIM;
  const float* Lb = L + (size_t)bb * NDIM;
  u16* ob = outH + (size_t)bb * CDIM * NDIM;
  f32x4 zero4 = {0.f, 0.f, 0.f, 0.f};
  f32x4 acc[4];
  for (int i = 0; i < 4; i++) acc[i] = zero4;

  for (int k0 = 0; k0 < CDIM; k0 += 32) {
    short8 a = *(const short8*)&W[(size_t)(o0 + li) * CDIM + k0 + q * 8];
#pragma unroll
    for (int ns = 0; ns < 4; ns++) {
      short8 bf = *(const short8*)&xtb[(size_t)(ntile + ns * 16 + li) * CDIM + k0 + q * 8];
      acc[ns] = MFMA16(a, bf, acc[ns]);
    }
  }
  float bv[4];
#pragma unroll
  for (int reg = 0; reg < 4; reg++) bv[reg] = bias[o0 + q * 4 + reg];
#pragma unroll
  for (int ns = 0; ns < 4; ns++) {
    int n = ntile + ns * 16 + li;
    float ex = exp2f(-Lb[n]);
#pragma unroll
    for (int reg = 0; reg < 4; reg++) {
      int c = o0 + q * 4 + reg;
      ob[(size_t)c * NDIM + n] = (u16)f2bf((acc[ns][reg] + bv[reg]) * ex);
    }
  }
}

// ---------------------------------------------------------------------------
// apply v15: out[c][m] = gamma * sum_n h'[c,n]*2^{S2[n,m]} + x[c][m]
// v14 post-mortem: MFMA32 rewrite put per-ks global h' loads directly
// before their MFMAs (compiler kept VGPR=60, no prefetch room) -> exposed
// L2 latency in the inner loop, 138->199us. REVERT to v13's exact consumer
// schedule (MFMA16, one-kh-lookahead ah rotation, setprio, lgkm-only
// barrier) and apply ONE floor cut:
//  - consumer reshape (m=128,c=32) -> (m=64,c=64): each consumer wave
//    reads only its m-half of P. CU LDS reads/chunk: 256KB -> 128KB
//    (floor ~3.1k -> ~1.5k cyc). MFMA count & acc (64 VGPR) unchanged;
//    h' traffic doubles but is L2-resident (v12 pin; R4 proved vmem
//    non-binding). ah rotation [2][4] = 32 VGPR (was 16).
//  - Pt row pad 132 -> 136 u16 (272B stride = 16 mod 128B): read-start
//    banks cover all 32 banks (264B gave even-only starts). LDS 68KB.
//  - base-2 exp (v14 item 3) KEPT: proven correct, fewer VALU ops.
// Roles: producer (w even, pidx=w>>1): score m-subtile pidx, full 128n.
//        consumer (w odd, cidx=w>>1): mbase=(cidx>>2)*64, c0=(cidx&3)*64;
//        16 ds_read_b128 + 16 global short8 + 64 MFMA16 per chunk.
// VGPR budget: acc 64 + ah 32 + addr/temps ~15 -> ~110-120 under
// (1024,4)=128. WATCH: VGPR>=128 or scratch => v10/v14 failure mode.
// ---------------------------------------------------------------------------
__global__ __launch_bounds__(1024, 4) void apply_kernel(
    const u16* __restrict__ ft, const u16* __restrict__ gt,
    const u16* __restrict__ h,
    const float* __restrict__ x1, const float* __restrict__ x2,
    const float* __restrict__ gamma1, const float* __restrict__ gamma2,
    float* __restrict__ out) {
  __shared__ u16 Pt[2][128][136];  // [buf][m][n128+pad], 272B row stride
  const int t = threadIdx.x, w = t >> 6, l = t & 63, li = l & 15, q = l >> 4;
  const int bid = blockIdx.x;
  const int bb = bid & 7;             // XCD pin (v12; h'/ft/gt L2-resident)
  const int mtile = (bid >> 3) * 128;
  const int br = bb >> 2, b = bb & 3;
  const u16* ftb = ft + (size_t)bb * NDIM * KD;
  const u16* gtb = gt + (size_t)bb * NDIM * KD;
  const u16* hb = h + (size_t)bb * CDIM * NDIM;
  const float* xb = (br ? x2 : x1) + (size_t)b * CDIM * NDIM;
  const float gmv = br ? gamma2[0] : gamma1[0];
  float* ob = out + (size_t)bb * CDIM * NDIM;

  const bool producer = (w & 1) == 0;
  const int pidx = w >> 1;            // producer: m-subtile 0..7
  const int cidx = w >> 1;            // consumer index 0..7
  const int mbase = (cidx >> 2) * 64; // consumer: m-half within 128-m tile
  const int c0 = (cidx & 3) * 64;     // consumer: 64-channel range
  f32x4 zero4 = {0.f, 0.f, 0.f, 0.f};

  short8 gfrag;
  if (producer)
    gfrag = *(const short8*)&gtb[(size_t)(mtile + pidx * 16 + li) * KD + q * 8];

  f32x4 acc[4][4];  // [ms][cs] : D[m=mtile+mbase+ms*16+q*4+reg][c=c0+cs*16+li]
#pragma unroll
  for (int i = 0; i < 4; i++)
#pragma unroll
    for (int j = 0; j < 4; j++) acc[i][j] = zero4;

  for (int i = 0; i <= 32; i++) {
    if (producer) {
      if (i < 32) {
        const int n0 = i * 128, buf = i & 1;
        short8 af[8];
#pragma unroll
        for (int j = 0; j < 8; j++)
          af[j] = *(const short8*)&ftb[(size_t)(n0 + j * 16 + li) * KD + q * 8];
#pragma unroll
        for (int j = 0; j < 8; j++) {
          f32x4 S = MFMA16(af[j], gfrag, zero4);
          u32 p0 = pack_bf16x2(exp2f(S[0]), exp2f(S[1]));
          u32 p1 = pack_bf16x2(exp2f(S[2]), exp2f(S[3]));
          // P[m = mtile+pidx*16+li][n = j*16+q*4 .. +3] = 2^{S2[n,m]}
          *(uint2*)&Pt[buf][pidx * 16 + li][j * 16 + q * 4] = make_uint2(p0, p1);
        }
      }
    } else {
      if (i >= 1) {
        const int n0 = (i - 1) * 128, buf = (i - 1) & 1;
        short8 ah[2][4];  // rotating [kh&1][cs]; static after unroll
#pragma unroll
        for (int cs = 0; cs < 4; cs++)
          ah[0][cs] = *(const short8*)
              &hb[(size_t)(c0 + cs * 16 + li) * NDIM + n0 + q * 8];
        __builtin_amdgcn_s_setprio(1);
#pragma unroll
        for (int kh = 0; kh < 4; kh++) {
          if (kh < 3) {
#pragma unroll
            for (int cs = 0; cs < 4; cs++)
              ah[(kh + 1) & 1][cs] = *(const short8*)
                  &hb[(size_t)(c0 + cs * 16 + li) * NDIM + n0 + (kh + 1) * 32 + q * 8];
          }
#pragma unroll
          for (int ms = 0; ms < 4; ms++) {
            short8 bm = *(const short8*)&Pt[buf][mbase + ms * 16 + li][kh * 32 + q * 8];
            acc[ms][0] = MFMA16(bm, ah[kh & 1][0], acc[ms][0]);
            acc[ms][1] = MFMA16(bm, ah[kh & 1][1], acc[ms][1]);
            acc[ms][2] = MFMA16(bm, ah[kh & 1][2], acc[ms][2]);
            acc[ms][3] = MFMA16(bm, ah[kh & 1][3], acc[ms][3]);
          }
        }
        __builtin_amdgcn_s_setprio(0);
      }
    }
    // LDS-only barrier: publish of P_i visible; consumer reads of the
    // other buffer retired; vmem (af/ah) never drained here.
    asm volatile("s_waitcnt lgkmcnt(0)" ::: "memory");
    __builtin_amdgcn_s_barrier();
  }

  // epilogue: consumers hold the full output; float4 stores (m contiguous)
  if (!producer) {
#pragma unroll
    for (int ms = 0; ms < 4; ms++) {
#pragma unroll
      for (int cs = 0; cs < 4; cs++) {
        int c = c0 + cs * 16 + li;
        int m = mtile + mbase + ms * 16 + q * 4;
        size_t idx = (size_t)c * NDIM + m;
        float4 xv = *(const float4*)&xb[idx];
        float4 o;
        o.x = gmv * acc[ms][cs][0] + xv.x;
        o.y = gmv * acc[ms][cs][1] + xv.y;
        o.z = gmv * acc[ms][cs][2] + xv.z;
        o.w = gmv * acc[ms][cs][3] + xv.w;
        *(float4*)&ob[idx] = o;
      }
    }
  }
}

// ---------------------------------------------------------------------------
extern "C" void kernel_launch(void* const* d_in, const int* in_sizes, int n_in,
                              void* d_out, int out_size, void* d_ws, size_t ws_size,
                              hipStream_t stream) {
  const float* x1 = (const float*)d_in[0];
  const float* x2 = (const float*)d_in[1];
  const float* f_w = (const float*)d_in[2];
  const float* f_b = (const float*)d_in[3];
  const float* g_w = (const float*)d_in[4];
  const float* g_b = (const float*)d_in[5];
  const float* h1_w = (const float*)d_in[6];
  const float* h1_b = (const float*)d_in[7];
  const float* h2_w = (const float*)d_in[8];
  const float* h2_b = (const float*)d_in[9];
  const float* gamma1 = (const float*)d_in[10];
  const float* gamma2 = (const float*)d_in[11];
  float* out = (float*)d_out;

  char* ws = (char*)d_ws;
  u16* xt  = (u16*)(ws);                          // [8][4096][256]  16 MB
  u16* wh  = (u16*)(ws + 16777216);               // [8][256][4096]  16 MB
  u16* ftw = (u16*)(ws + 33554432);               // [8][4096][32]    2 MB
  u16* gtw = (u16*)(ws + 35651584);               // [8][4096][32]    2 MB
  u16* wWh = (u16*)(ws + 37748736);               // [2][256][256]  256 KB
  u16* wWf = (u16*)(ws + 38010880);               // [32][256]       16 KB
  u16* wWg = (u16*)(ws + 38027264);               // [32][256]       16 KB
  float* Lw = (float*)(ws + 38043648);            // [8][4096]      128 KB

  cast_all_kernel<<<576, 256, 0, stream>>>(h1_w, h2_w, f_w, g_w, wWh);

  transpose_cast_kernel<<<dim3(64, 4, 8), 256, 0, stream>>>(x1, x2, xt);

  conv_fg_kernel<<<dim3(64, 8), 256, 0, stream>>>(wWf, f_b, wWg, g_b, xt, ftw, gtw);

  stats_kernel<<<dim3(128, 4, 2), 256, 0, stream>>>(ftw, gtw, Lw);

  conv_h_kernel<<<dim3(64, 4, 8), 256, 0, stream>>>(wWh, h1_b, h2_b, xt, Lw, wh);

  apply_kernel<<<256, 1024, 0, stream>>>(ftw, gtw, wh, x1, x2,
                                         gamma1, gamma2, out);
}

// Round 8
// 312.499 us; speedup vs baseline: 1.2252x; 1.2252x over previous
//
#include <hip/hip_runtime.h>
#include <hip/hip_bf16.h>
#include <math.h>

#define NDIM 4096
#define CDIM 256
#define KD   32
#define SCALE 0.17677669529663687f   // 1/sqrt(32)
// ALPHA = SCALE * log2(e): folded into Wf so scores are base-2 exponents
#define ALPHA (0.17677669529663687f * 1.44269504088896341f)
#define SHIFT2 11.541560327111707f   // 8 * log2(e)

typedef __attribute__((ext_vector_type(8))) short short8;  // 8 bf16 = 4 VGPRs
typedef __attribute__((ext_vector_type(4))) float f32x4;
typedef unsigned short u16;
typedef unsigned int u32;

__device__ __forceinline__ u32 f2bf(float x) {  // fp32 -> bf16 bits, RNE
  union { float f; u32 u; } v; v.f = x;
  return (v.u + 0x7FFFu + ((v.u >> 16) & 1u)) >> 16;
}

__device__ __forceinline__ u32 pack_bf16x2(float a, float b) {
  __hip_bfloat162 h2 = __float22bfloat162_rn(make_float2(a, b));
  u32 r;
  __builtin_memcpy(&r, &h2, 4);
  return r;
}

#define MFMA16(a, b, c) __builtin_amdgcn_mfma_f32_16x16x32_bf16((a), (b), (c), 0, 0, 0)

// ---------------------------------------------------------------------------
// cast all weights fp32 -> bf16. f-weights pre-scaled by ALPHA so that
// score MFMAs directly produce base-2 exponents (exp2 = native v_exp_f32).
// ---------------------------------------------------------------------------
__global__ void cast_all_kernel(const float* __restrict__ h1w,
                                const float* __restrict__ h2w,
                                const float* __restrict__ fw,
                                const float* __restrict__ gw,
                                u16* __restrict__ dst) {
  int i = blockIdx.x * 256 + threadIdx.x;
  float v;
  if (i < 65536) v = h1w[i];
  else if (i < 131072) v = h2w[i - 65536];
  else if (i < 139264) v = fw[i - 131072] * ALPHA;
  else v = gw[i - 139264];
  dst[i] = (u16)f2bf(v);
}

// ---------------------------------------------------------------------------
// x[b][C][n] fp32 -> xT[bb][n][C] bf16
// ---------------------------------------------------------------------------
__global__ __launch_bounds__(256) void transpose_cast_kernel(
    const float* __restrict__ x1, const float* __restrict__ x2,
    u16* __restrict__ xt) {
  __shared__ float ts[64][68];
  const int t = threadIdx.x;
  const int ntile = blockIdx.x * 64, Ctile = blockIdx.y * 64, z = blockIdx.z;
  const float* xb = ((z >> 2) ? x2 : x1) + (size_t)(z & 3) * CDIM * NDIM;
  u16* xtb = xt + (size_t)z * NDIM * CDIM;
  const int r = t >> 4, c4 = (t & 15) * 4;
#pragma unroll
  for (int i = 0; i < 4; i++) {
    float4 v = *(const float4*)&xb[(size_t)(Ctile + r + i * 16) * NDIM + ntile + c4];
    *(float4*)&ts[r + i * 16][c4] = v;
  }
  __syncthreads();
  const int n = t >> 2, Cg = (t & 3) * 16;
  u32 pk[8];
#pragma unroll
  for (int j = 0; j < 8; j++) {
    u32 lo = f2bf(ts[Cg + 2 * j][n]);
    u32 hi = f2bf(ts[Cg + 2 * j + 1][n]);
    pk[j] = lo | (hi << 16);
  }
  uint4* dst = (uint4*)&xtb[(size_t)(ntile + n) * CDIM + Ctile + Cg];
  dst[0] = make_uint4(pk[0], pk[1], pk[2], pk[3]);
  dst[1] = make_uint4(pk[4], pk[5], pk[6], pk[7]);
}

// ---------------------------------------------------------------------------
// conv f+g fused via MFMA. block 256 (4 waves), tile 32o x 64n, grid (64, 8)
// f-bias scaled by ALPHA to match pre-scaled Wf.
// ---------------------------------------------------------------------------
__global__ __launch_bounds__(256) void conv_fg_kernel(
    const u16* __restrict__ Wf, const float* __restrict__ fbias,
    const u16* __restrict__ Wg, const float* __restrict__ gbias,
    const u16* __restrict__ xt, u16* __restrict__ ftT, u16* __restrict__ gtT) {
  const int t = threadIdx.x, w = t >> 6, l = t & 63, li = l & 15, q = l >> 4;
  const int ntile = blockIdx.x * 64, bb = blockIdx.y;
  const u16* xtb = xt + (size_t)bb * NDIM * CDIM;
  f32x4 zero4 = {0.f, 0.f, 0.f, 0.f};
  f32x4 acc[2][2];
  for (int i = 0; i < 2; i++) for (int j = 0; j < 2; j++) acc[i][j] = zero4;
  const int nrow = ntile + w * 16 + li;

  for (int k0 = 0; k0 < CDIM; k0 += 32) {
    short8 bx = *(const short8*)&xtb[(size_t)nrow * CDIM + k0 + q * 8];
    short8 af0 = *(const short8*)&Wf[(size_t)(li) * CDIM + k0 + q * 8];
    short8 af1 = *(const short8*)&Wf[(size_t)(16 + li) * CDIM + k0 + q * 8];
    short8 ag0 = *(const short8*)&Wg[(size_t)(li) * CDIM + k0 + q * 8];
    short8 ag1 = *(const short8*)&Wg[(size_t)(16 + li) * CDIM + k0 + q * 8];
    acc[0][0] = MFMA16(af0, bx, acc[0][0]);
    acc[0][1] = MFMA16(af1, bx, acc[0][1]);
    acc[1][0] = MFMA16(ag0, bx, acc[1][0]);
    acc[1][1] = MFMA16(ag1, bx, acc[1][1]);
  }
  u16* outs[2] = {ftT + (size_t)bb * NDIM * KD, gtT + (size_t)bb * NDIM * KD};
  const float* biases[2] = {fbias, gbias};
  const float bscale[2] = {ALPHA, 1.0f};
#pragma unroll
  for (int fg = 0; fg < 2; fg++) {
#pragma unroll
    for (int os = 0; os < 2; os++) {
      float b0 = biases[fg][os * 16 + q * 4 + 0] * bscale[fg];
      float b1 = biases[fg][os * 16 + q * 4 + 1] * bscale[fg];
      float b2 = biases[fg][os * 16 + q * 4 + 2] * bscale[fg];
      float b3 = biases[fg][os * 16 + q * 4 + 3] * bscale[fg];
      u32 p0 = f2bf(acc[fg][os][0] + b0) | (f2bf(acc[fg][os][1] + b1) << 16);
      u32 p1 = f2bf(acc[fg][os][2] + b2) | (f2bf(acc[fg][os][3] + b3) << 16);
      *(uint2*)&outs[fg][(size_t)nrow * KD + os * 16 + q * 4] = make_uint2(p0, p1);
    }
  }
}

// ---------------------------------------------------------------------------
// stats (base-2): L2[n] = SHIFT2 + log2(sum_m 2^(S2[n,m]-SHIFT2)),
// where S2 = s*SCALE*log2e (ft pre-scaled). L2 = L*log2e.
// ---------------------------------------------------------------------------
__global__ __launch_bounds__(256) void stats_kernel(
    const u16* __restrict__ ft, const u16* __restrict__ gt,
    float* __restrict__ L) {
  __shared__ float zred[32][64];
  const int t = threadIdx.x, w = t >> 6, l = t & 63, li = l & 15, q = l >> 4;
  const int n0 = blockIdx.x * 32;
  const int bb = blockIdx.z * 4 + blockIdx.y;
  const u16* ftb = ft + (size_t)bb * NDIM * KD;
  const u16* gtb = gt + (size_t)bb * NDIM * KD;
  f32x4 zero4 = {0.f, 0.f, 0.f, 0.f};

  short8 a0 = *(const short8*)&ftb[(size_t)(n0 + li) * KD + q * 8];
  short8 a1 = *(const short8*)&ftb[(size_t)(n0 + 16 + li) * KD + q * 8];
  f32x4 z0 = zero4, z1 = zero4;

#pragma unroll 2
  for (int it = 0; it < 64; it++) {
    int m = (it * 4 + w) * 16;
    short8 bf = *(const short8*)&gtb[(size_t)(m + li) * KD + q * 8];
    f32x4 S0 = MFMA16(a0, bf, zero4);
    f32x4 S1 = MFMA16(a1, bf, zero4);
#pragma unroll
    for (int reg = 0; reg < 4; reg++) {
      z0[reg] += exp2f(S0[reg] - SHIFT2);
      z1[reg] += exp2f(S1[reg] - SHIFT2);
    }
  }
#pragma unroll
  for (int reg = 0; reg < 4; reg++) {
    zred[q * 4 + reg][w * 16 + li] = z0[reg];
    zred[16 + q * 4 + reg][w * 16 + li] = z1[reg];
  }
  __syncthreads();
  const int r = t >> 3, i8 = t & 7;
  float4 s1 = *(const float4*)&zred[r][i8 * 8];
  float4 s2 = *(const float4*)&zred[r][i8 * 8 + 4];
  float sum = s1.x + s1.y + s1.z + s1.w + s2.x + s2.y + s2.z + s2.w;
  sum += __shfl_xor(sum, 1, 8);
  sum += __shfl_xor(sum, 2, 8);
  sum += __shfl_xor(sum, 4, 8);
  if (i8 == 0) L[(size_t)bb * NDIM + n0 + r] = SHIFT2 + __log2f(sum);
}

// ---------------------------------------------------------------------------
// conv h (both branches) via MFMA, with 2^{-L2[n]} folded into the output:
// h'[c][n] = (W @ x + bias)[c][n] * 2^{-L2[n]}.
// ---------------------------------------------------------------------------
__global__ __launch_bounds__(256) void conv_h_kernel(
    const u16* __restrict__ Wall, const float* __restrict__ b1,
    const float* __restrict__ b2, const u16* __restrict__ xt,
    const float* __restrict__ L, u16* __restrict__ outH) {
  const int t = threadIdx.x, w = t >> 6, l = t & 63, li = l & 15, q = l >> 4;
  const int ntile = blockIdx.x * 64;
  const int o0 = blockIdx.y * 64 + w * 16;
  const int bb = blockIdx.z, branch = bb >> 2;
  const u16* W = Wall + (size_t)branch * CDIM * CDIM;
  const float* bias = branch ? b2 : b1;
  const u16* xtb = xt + (size_t)bb * NDIM * CDIM;
  const float* Lb = L + (size_t)bb * NDIM;
  u16* ob = outH + (size_t)bb * CDIM * NDIM;
  f32x4 zero4 = {0.f, 0.f, 0.f, 0.f};
  f32x4 acc[4];
  for (int i = 0; i < 4; i++) acc[i] = zero4;

  for (int k0 = 0; k0 < CDIM; k0 += 32) {
    short8 a = *(const short8*)&W[(size_t)(o0 + li) * CDIM + k0 + q * 8];
#pragma unroll
    for (int ns = 0; ns < 4; ns++) {
      short8 bf = *(const short8*)&xtb[(size_t)(ntile + ns * 16 + li) * CDIM + k0 + q * 8];
      acc[ns] = MFMA16(a, bf, acc[ns]);
    }
  }
  float bv[4];
#pragma unroll
  for (int reg = 0; reg < 4; reg++) bv[reg] = bias[o0 + q * 4 + reg];
#pragma unroll
  for (int ns = 0; ns < 4; ns++) {
    int n = ntile + ns * 16 + li;
    float ex = exp2f(-Lb[n]);
#pragma unroll
    for (int reg = 0; reg < 4; reg++) {
      int c = o0 + q * 4 + reg;
      ob[(size_t)c * NDIM + n] = (u16)f2bf((acc[ns][reg] + bv[reg]) * ex);
    }
  }
}

// ---------------------------------------------------------------------------
// apply v16: out[c][m] = gamma * sum_n h'[c,n]*2^{S2[n,m]} + x[c][m]
// v16 = EXACT v13 shell (8P/8C role-split, pad 132 = 0-conflict proven,
// c=32/consumer, ah rotation, setprio, lgkm-only barrier) + ONE mechanism:
// BATCHED consumer ds_reads.
// v15 post-mortem: pad 136 CREATED 6.3M conflicts (272B = 4 banks mod 32,
// li/li+8 collide; 264B was conflict-free) and c=64 reshape broke the
// interleave -> 202us. Deeper: VGPR_Count ~60 in EVERY variant => compiler
// schedules loads read->use pairwise with latency exposed (v13 consumer:
// 8x per kh: ds_read(~150cyc) -> 2 MFMA(39cyc) serialized ~ 6k cyc/wave --
// the only model matching measured 10.4k/chunk when pipe floors are 2.8k).
// Fix: per kh, TWO half-batches: {4 ds_reads -> sched_barrier(0) -> 8
// MFMAs}. The sched_barrier pins the batch (reads can't sink, MFMAs can't
// hoist); batch-of-4 keeps live bm at 16 VGPR (acc 64 lives in AGPRs);
// next half-batch's reads may hoist into current MFMA group -> steady-
// state latency hiding. SIGNAL: VGPR_Count should RISE to ~80-110; if it
// stays <=64 the compiler defeated the batch and result will be v13-flat.
// base-2 exp kept everywhere (proven, absmax unchanged since v14).
// ---------------------------------------------------------------------------
__global__ __launch_bounds__(1024, 4) void apply_kernel(
    const u16* __restrict__ ft, const u16* __restrict__ gt,
    const u16* __restrict__ h,
    const float* __restrict__ x1, const float* __restrict__ x2,
    const float* __restrict__ gamma1, const float* __restrict__ gamma2,
    float* __restrict__ out) {
  __shared__ u16 Pt[2][128][132];  // [buf][m][n128+pad], 264B row stride
  const int t = threadIdx.x, w = t >> 6, l = t & 63, li = l & 15, q = l >> 4;
  const int bid = blockIdx.x;
  const int bb = bid & 7;             // XCD pin (v12; h'/ft/gt L2-resident)
  const int mtile = (bid >> 3) * 128;
  const int br = bb >> 2, b = bb & 3;
  const u16* ftb = ft + (size_t)bb * NDIM * KD;
  const u16* gtb = gt + (size_t)bb * NDIM * KD;
  const u16* hb = h + (size_t)bb * CDIM * NDIM;
  const float* xb = (br ? x2 : x1) + (size_t)b * CDIM * NDIM;
  const float gmv = br ? gamma2[0] : gamma1[0];
  float* ob = out + (size_t)bb * CDIM * NDIM;

  const bool producer = (w & 1) == 0;
  const int pidx = w >> 1;            // producer: m-subtile 0..7
  const int c0 = (w >> 1) * 32;       // consumer: 32-channel range
  f32x4 zero4 = {0.f, 0.f, 0.f, 0.f};

  short8 gfrag;
  if (producer)
    gfrag = *(const short8*)&gtb[(size_t)(mtile + pidx * 16 + li) * KD + q * 8];

  f32x4 acc[8][2];  // [ms][cs] : D[m=ms*16+q*4+reg][c=c0+cs*16+li]
#pragma unroll
  for (int i = 0; i < 8; i++)
#pragma unroll
    for (int j = 0; j < 2; j++) acc[i][j] = zero4;

  for (int i = 0; i <= 32; i++) {
    if (producer) {
      if (i < 32) {
        const int n0 = i * 128, buf = i & 1;
        short8 af[8];
#pragma unroll
        for (int j = 0; j < 8; j++)
          af[j] = *(const short8*)&ftb[(size_t)(n0 + j * 16 + li) * KD + q * 8];
#pragma unroll
        for (int j = 0; j < 8; j++) {
          f32x4 S = MFMA16(af[j], gfrag, zero4);
          u32 p0 = pack_bf16x2(exp2f(S[0]), exp2f(S[1]));
          u32 p1 = pack_bf16x2(exp2f(S[2]), exp2f(S[3]));
          // P[m = mtile+pidx*16+li][n = j*16+q*4 .. +3] = 2^{S2[n,m]}
          *(uint2*)&Pt[buf][pidx * 16 + li][j * 16 + q * 4] = make_uint2(p0, p1);
        }
      }
    } else {
      if (i >= 1) {
        const int n0 = (i - 1) * 128, buf = (i - 1) & 1;
        short8 ah[2][2];  // rotating [kh&1][cs]; static after unroll
#pragma unroll
        for (int cs = 0; cs < 2; cs++)
          ah[0][cs] = *(const short8*)
              &hb[(size_t)(c0 + cs * 16 + li) * NDIM + n0 + q * 8];
        __builtin_amdgcn_s_setprio(1);
#pragma unroll
        for (int kh = 0; kh < 4; kh++) {
          if (kh < 3) {
#pragma unroll
            for (int cs = 0; cs < 2; cs++)
              ah[(kh + 1) & 1][cs] = *(const short8*)
                  &hb[(size_t)(c0 + cs * 16 + li) * NDIM + n0 + (kh + 1) * 32 + q * 8];
          }
#pragma unroll
          for (int half = 0; half < 2; half++) {
            short8 bm[4];
#pragma unroll
            for (int mi = 0; mi < 4; mi++) {
              const int ms = half * 4 + mi;
              bm[mi] = *(const short8*)&Pt[buf][ms * 16 + li][kh * 32 + q * 8];
            }
            __builtin_amdgcn_sched_barrier(0);  // pin the 4-read batch
#pragma unroll
            for (int mi = 0; mi < 4; mi++) {
              const int ms = half * 4 + mi;
              acc[ms][0] = MFMA16(bm[mi], ah[kh & 1][0], acc[ms][0]);
              acc[ms][1] = MFMA16(bm[mi], ah[kh & 1][1], acc[ms][1]);
            }
          }
        }
        __builtin_amdgcn_s_setprio(0);
      }
    }
    // LDS-only barrier: publish of P_i visible; consumer reads of the
    // other buffer retired; vmem (af/ah) never drained here.
    asm volatile("s_waitcnt lgkmcnt(0)" ::: "memory");
    __builtin_amdgcn_s_barrier();
  }

  // epilogue: consumers hold the full output; float4 stores (m contiguous)
  if (!producer) {
#pragma unroll
    for (int ms = 0; ms < 8; ms++) {
#pragma unroll
      for (int cs = 0; cs < 2; cs++) {
        int c = c0 + cs * 16 + li;
        int m = mtile + ms * 16 + q * 4;
        size_t idx = (size_t)c * NDIM + m;
        float4 xv = *(const float4*)&xb[idx];
        float4 o;
        o.x = gmv * acc[ms][cs][0] + xv.x;
        o.y = gmv * acc[ms][cs][1] + xv.y;
        o.z = gmv * acc[ms][cs][2] + xv.z;
        o.w = gmv * acc[ms][cs][3] + xv.w;
        *(float4*)&ob[idx] = o;
      }
    }
  }
}

// ---------------------------------------------------------------------------
extern "C" void kernel_launch(void* const* d_in, const int* in_sizes, int n_in,
                              void* d_out, int out_size, void* d_ws, size_t ws_size,
                              hipStream_t stream) {
  const float* x1 = (const float*)d_in[0];
  const float* x2 = (const float*)d_in[1];
  const float* f_w = (const float*)d_in[2];
  const float* f_b = (const float*)d_in[3];
  const float* g_w = (const float*)d_in[4];
  const float* g_b = (const float*)d_in[5];
  const float* h1_w = (const float*)d_in[6];
  const float* h1_b = (const float*)d_in[7];
  const float* h2_w = (const float*)d_in[8];
  const float* h2_b = (const float*)d_in[9];
  const float* gamma1 = (const float*)d_in[10];
  const float* gamma2 = (const float*)d_in[11];
  float* out = (float*)d_out;

  char* ws = (char*)d_ws;
  u16* xt  = (u16*)(ws);                          // [8][4096][256]  16 MB
  u16* wh  = (u16*)(ws + 16777216);               // [8][256][4096]  16 MB
  u16* ftw = (u16*)(ws + 33554432);               // [8][4096][32]    2 MB
  u16* gtw = (u16*)(ws + 35651584);               // [8][4096][32]    2 MB
  u16* wWh = (u16*)(ws + 37748736);               // [2][256][256]  256 KB
  u16* wWf = (u16*)(ws + 38010880);               // [32][256]       16 KB
  u16* wWg = (u16*)(ws + 38027264);               // [32][256]       16 KB
  float* Lw = (float*)(ws + 38043648);            // [8][4096]      128 KB

  cast_all_kernel<<<576, 256, 0, stream>>>(h1_w, h2_w, f_w, g_w, wWh);

  transpose_cast_kernel<<<dim3(64, 4, 8), 256, 0, stream>>>(x1, x2, xt);

  conv_fg_kernel<<<dim3(64, 8), 256, 0, stream>>>(wWf, f_b, wWg, g_b, xt, ftw, gtw);

  stats_kernel<<<dim3(128, 4, 2), 256, 0, stream>>>(ftw, gtw, Lw);

  conv_h_kernel<<<dim3(64, 4, 8), 256, 0, stream>>>(wWh, h1_b, h2_b, xt, Lw, wh);

  apply_kernel<<<256, 1024, 0, stream>>>(ftw, gtw, wh, x1, x2,
                                         gamma1, gamma2, out);
}

// Round 9
// 301.284 us; speedup vs baseline: 1.2708x; 1.0372x over previous
//
#include <hip/hip_runtime.h>
#include <hip/hip_bf16.h>
#include <math.h>

#define NDIM 4096
#define CDIM 256
#define KD   32
#define SCALE 0.17677669529663687f   // 1/sqrt(32)
// ALPHA = SCALE * log2(e): folded into Wf so scores are base-2 exponents
#define ALPHA (0.17677669529663687f * 1.44269504088896341f)
#define SHIFT2 11.541560327111707f   // 8 * log2(e)

typedef __attribute__((ext_vector_type(8))) short short8;  // 8 bf16 = 4 VGPRs
typedef __attribute__((ext_vector_type(4))) float f32x4;
typedef unsigned short u16;
typedef unsigned int u32;

__device__ __forceinline__ u32 f2bf(float x) {  // fp32 -> bf16 bits, RNE
  union { float f; u32 u; } v; v.f = x;
  return (v.u + 0x7FFFu + ((v.u >> 16) & 1u)) >> 16;
}

__device__ __forceinline__ u32 pack_bf16x2(float a, float b) {
  __hip_bfloat162 h2 = __float22bfloat162_rn(make_float2(a, b));
  u32 r;
  __builtin_memcpy(&r, &h2, 4);
  return r;
}

// load 8 consecutive fp32 weights, scale, cast to bf16 short8 (RNE, same
// bits as the old cast_all path)
__device__ __forceinline__ short8 load_w8(const float* __restrict__ p,
                                          float scale) {
  float4 v0 = *(const float4*)p;
  float4 v1 = *(const float4*)(p + 4);
  short8 r;
  r[0] = (short)f2bf(v0.x * scale);
  r[1] = (short)f2bf(v0.y * scale);
  r[2] = (short)f2bf(v0.z * scale);
  r[3] = (short)f2bf(v0.w * scale);
  r[4] = (short)f2bf(v1.x * scale);
  r[5] = (short)f2bf(v1.y * scale);
  r[6] = (short)f2bf(v1.z * scale);
  r[7] = (short)f2bf(v1.w * scale);
  return r;
}

#define MFMA16(a, b, c) __builtin_amdgcn_mfma_f32_16x16x32_bf16((a), (b), (c), 0, 0, 0)

// ---------------------------------------------------------------------------
// tfg: transpose+cast x -> xt  AND  conv f+g, fused per (64-n, bb) block.
// Phase A: 4 C-tiles of 64x64 fp32 -> bf16 transpose, written to global xt.
// Phase B: conv_fg for the same 64 n rows, reading xt back (same block wrote
// it; __syncthreads drains the stores; addresses never previously cached in
// L1, so reads fetch fresh lines from L2). W cast fp32->bf16 inline (ALPHA
// folded into Wf for base-2 exponents downstream).
// Grid: 1-D 512, bb = bid&7 (XCD pin: xt/ft/gt stay in this XCD's L2 for
// the downstream kernels, which use the same pin).
// ---------------------------------------------------------------------------
__global__ __launch_bounds__(256) void tfg_kernel(
    const float* __restrict__ x1, const float* __restrict__ x2,
    const float* __restrict__ fw, const float* __restrict__ fbias,
    const float* __restrict__ gw, const float* __restrict__ gbias,
    u16* __restrict__ xt, u16* __restrict__ ftT, u16* __restrict__ gtT) {
  __shared__ float ts[64][68];
  const int t = threadIdx.x;
  const int bid = blockIdx.x;
  const int bb = bid & 7;               // XCD pin
  const int ntile = (bid >> 3) * 64;
  const float* xb = ((bb >> 2) ? x2 : x1) + (size_t)(bb & 3) * CDIM * NDIM;
  u16* xtb = xt + (size_t)bb * NDIM * CDIM;

  // ---- phase A: transpose+cast, all 4 C-tiles ----
  const int r = t >> 4, c4 = (t & 15) * 4;
  const int n = t >> 2, Cg = (t & 3) * 16;
#pragma unroll
  for (int ct = 0; ct < 4; ct++) {
    const int Ctile = ct * 64;
#pragma unroll
    for (int i = 0; i < 4; i++) {
      float4 v = *(const float4*)&xb[(size_t)(Ctile + r + i * 16) * NDIM + ntile + c4];
      *(float4*)&ts[r + i * 16][c4] = v;
    }
    __syncthreads();
    u32 pk[8];
#pragma unroll
    for (int j = 0; j < 8; j++) {
      u32 lo = f2bf(ts[Cg + 2 * j][n]);
      u32 hi = f2bf(ts[Cg + 2 * j + 1][n]);
      pk[j] = lo | (hi << 16);
    }
    uint4* dst = (uint4*)&xtb[(size_t)(ntile + n) * CDIM + Ctile + Cg];
    dst[0] = make_uint4(pk[0], pk[1], pk[2], pk[3]);
    dst[1] = make_uint4(pk[4], pk[5], pk[6], pk[7]);
    __syncthreads();  // ts reuse + (last iter) xt stores drained before B
  }

  // ---- phase B: conv f+g for these 64 n rows ----
  const int w = t >> 6, l = t & 63, li = l & 15, q = l >> 4;
  f32x4 zero4 = {0.f, 0.f, 0.f, 0.f};
  f32x4 acc[2][2];
  for (int i = 0; i < 2; i++) for (int j = 0; j < 2; j++) acc[i][j] = zero4;
  const int nrow = ntile + w * 16 + li;

  for (int k0 = 0; k0 < CDIM; k0 += 32) {
    short8 bx = *(const short8*)&xtb[(size_t)nrow * CDIM + k0 + q * 8];
    short8 af0 = load_w8(&fw[(size_t)(li) * CDIM + k0 + q * 8], ALPHA);
    short8 af1 = load_w8(&fw[(size_t)(16 + li) * CDIM + k0 + q * 8], ALPHA);
    short8 ag0 = load_w8(&gw[(size_t)(li) * CDIM + k0 + q * 8], 1.0f);
    short8 ag1 = load_w8(&gw[(size_t)(16 + li) * CDIM + k0 + q * 8], 1.0f);
    acc[0][0] = MFMA16(af0, bx, acc[0][0]);
    acc[0][1] = MFMA16(af1, bx, acc[0][1]);
    acc[1][0] = MFMA16(ag0, bx, acc[1][0]);
    acc[1][1] = MFMA16(ag1, bx, acc[1][1]);
  }
  u16* outs[2] = {ftT + (size_t)bb * NDIM * KD, gtT + (size_t)bb * NDIM * KD};
  const float* biases[2] = {fbias, gbias};
  const float bscale[2] = {ALPHA, 1.0f};
#pragma unroll
  for (int fg = 0; fg < 2; fg++) {
#pragma unroll
    for (int os = 0; os < 2; os++) {
      float b0 = biases[fg][os * 16 + q * 4 + 0] * bscale[fg];
      float b1 = biases[fg][os * 16 + q * 4 + 1] * bscale[fg];
      float b2 = biases[fg][os * 16 + q * 4 + 2] * bscale[fg];
      float b3 = biases[fg][os * 16 + q * 4 + 3] * bscale[fg];
      u32 p0 = f2bf(acc[fg][os][0] + b0) | (f2bf(acc[fg][os][1] + b1) << 16);
      u32 p1 = f2bf(acc[fg][os][2] + b2) | (f2bf(acc[fg][os][3] + b3) << 16);
      *(uint2*)&outs[fg][(size_t)nrow * KD + os * 16 + q * 4] = make_uint2(p0, p1);
    }
  }
}

// ---------------------------------------------------------------------------
// sh: stats + conv_h fused per (32-n, bb) block.
// Phase A (old stats body): L2[n] = SHIFT2 + log2(sum_m 2^(S2[n,m]-SHIFT2))
// for the block's 32 n rows -> Lsh in LDS (no global L round-trip).
// Phase B (old conv_h): h'[c][n] = (W@x+b)[c][n] * 2^{-L2[n]} for o=256 (all
// channels, w*64 per wave), reading xt from L2 (XCD-pinned) and W fp32 with
// inline bf16 cast. Grid: 1-D 1024, bb = bid&7, ntile = (bid>>3)*32.
// ---------------------------------------------------------------------------
__global__ __launch_bounds__(256, 4) void sh_kernel(
    const u16* __restrict__ ft, const u16* __restrict__ gt,
    const float* __restrict__ h1w, const float* __restrict__ h2w,
    const float* __restrict__ b1, const float* __restrict__ b2,
    const u16* __restrict__ xt, u16* __restrict__ outH) {
  __shared__ float zred[32][64];
  __shared__ float Lsh[32];
  const int t = threadIdx.x, w = t >> 6, l = t & 63, li = l & 15, q = l >> 4;
  const int bid = blockIdx.x;
  const int bb = bid & 7;               // XCD pin (matches tfg/apply)
  const int ntile = (bid >> 3) * 32;
  const int branch = bb >> 2;
  const u16* ftb = ft + (size_t)bb * NDIM * KD;
  const u16* gtb = gt + (size_t)bb * NDIM * KD;
  const float* Wb = branch ? h2w : h1w;
  const float* bias = branch ? b2 : b1;
  const u16* xtb = xt + (size_t)bb * NDIM * CDIM;
  u16* ob = outH + (size_t)bb * CDIM * NDIM;
  f32x4 zero4 = {0.f, 0.f, 0.f, 0.f};

  // ---- phase A: stats for rows ntile..ntile+31 ----
  short8 a0 = *(const short8*)&ftb[(size_t)(ntile + li) * KD + q * 8];
  short8 a1 = *(const short8*)&ftb[(size_t)(ntile + 16 + li) * KD + q * 8];
  f32x4 z0 = zero4, z1 = zero4;
#pragma unroll 2
  for (int it = 0; it < 64; it++) {
    int m = (it * 4 + w) * 16;
    short8 bf = *(const short8*)&gtb[(size_t)(m + li) * KD + q * 8];
    f32x4 S0 = MFMA16(a0, bf, zero4);
    f32x4 S1 = MFMA16(a1, bf, zero4);
#pragma unroll
    for (int reg = 0; reg < 4; reg++) {
      z0[reg] += exp2f(S0[reg] - SHIFT2);
      z1[reg] += exp2f(S1[reg] - SHIFT2);
    }
  }
#pragma unroll
  for (int reg = 0; reg < 4; reg++) {
    zred[q * 4 + reg][w * 16 + li] = z0[reg];
    zred[16 + q * 4 + reg][w * 16 + li] = z1[reg];
  }
  __syncthreads();
  {
    const int rr = t >> 3, i8 = t & 7;
    float4 s1 = *(const float4*)&zred[rr][i8 * 8];
    float4 s2 = *(const float4*)&zred[rr][i8 * 8 + 4];
    float sum = s1.x + s1.y + s1.z + s1.w + s2.x + s2.y + s2.z + s2.w;
    sum += __shfl_xor(sum, 1, 8);
    sum += __shfl_xor(sum, 2, 8);
    sum += __shfl_xor(sum, 4, 8);
    if (i8 == 0) Lsh[rr] = SHIFT2 + __log2f(sum);
  }
  __syncthreads();

  // ---- phase B: conv_h (o0 = w*64, 64 channels per wave; n = 32) ----
  const int o0 = w * 64;
  f32x4 acch[4][2];  // [os][ns]
#pragma unroll
  for (int i = 0; i < 4; i++)
#pragma unroll
    for (int j = 0; j < 2; j++) acch[i][j] = zero4;

  for (int k0 = 0; k0 < CDIM; k0 += 32) {
    short8 aw[4];
#pragma unroll
    for (int os = 0; os < 4; os++)
      aw[os] = load_w8(&Wb[(size_t)(o0 + os * 16 + li) * CDIM + k0 + q * 8], 1.0f);
    short8 bx[2];
#pragma unroll
    for (int ns = 0; ns < 2; ns++)
      bx[ns] = *(const short8*)&xtb[(size_t)(ntile + ns * 16 + li) * CDIM + k0 + q * 8];
#pragma unroll
    for (int os = 0; os < 4; os++) {
      acch[os][0] = MFMA16(aw[os], bx[0], acch[os][0]);
      acch[os][1] = MFMA16(aw[os], bx[1], acch[os][1]);
    }
  }
  float bv[4][4];
#pragma unroll
  for (int os = 0; os < 4; os++)
#pragma unroll
    for (int reg = 0; reg < 4; reg++)
      bv[os][reg] = bias[o0 + os * 16 + q * 4 + reg];
#pragma unroll
  for (int ns = 0; ns < 2; ns++) {
    const int nloc = ns * 16 + li;
    const int nn = ntile + nloc;
    const float ex = exp2f(-Lsh[nloc]);
#pragma unroll
    for (int os = 0; os < 4; os++) {
#pragma unroll
      for (int reg = 0; reg < 4; reg++) {
        int c = o0 + os * 16 + q * 4 + reg;
        ob[(size_t)c * NDIM + nn] = (u16)f2bf((acch[os][ns][reg] + bv[os][reg]) * ex);
      }
    }
  }
}

// ---------------------------------------------------------------------------
// apply v16 (FROZEN from round 8: 130.5 us, MfmaUtil 24.7, 0 conflicts).
// 8P/8C role-split, pad 132, batched ds_reads + sched_barrier, setprio,
// lgkm-only barrier, XCD pin bb=bid&7.
// ---------------------------------------------------------------------------
__global__ __launch_bounds__(1024, 4) void apply_kernel(
    const u16* __restrict__ ft, const u16* __restrict__ gt,
    const u16* __restrict__ h,
    const float* __restrict__ x1, const float* __restrict__ x2,
    const float* __restrict__ gamma1, const float* __restrict__ gamma2,
    float* __restrict__ out) {
  __shared__ u16 Pt[2][128][132];  // [buf][m][n128+pad], 264B row stride
  const int t = threadIdx.x, w = t >> 6, l = t & 63, li = l & 15, q = l >> 4;
  const int bid = blockIdx.x;
  const int bb = bid & 7;             // XCD pin (h'/ft/gt L2-resident)
  const int mtile = (bid >> 3) * 128;
  const int br = bb >> 2, b = bb & 3;
  const u16* ftb = ft + (size_t)bb * NDIM * KD;
  const u16* gtb = gt + (size_t)bb * NDIM * KD;
  const u16* hb = h + (size_t)bb * CDIM * NDIM;
  const float* xb = (br ? x2 : x1) + (size_t)b * CDIM * NDIM;
  const float gmv = br ? gamma2[0] : gamma1[0];
  float* ob = out + (size_t)bb * CDIM * NDIM;

  const bool producer = (w & 1) == 0;
  const int pidx = w >> 1;            // producer: m-subtile 0..7
  const int c0 = (w >> 1) * 32;       // consumer: 32-channel range
  f32x4 zero4 = {0.f, 0.f, 0.f, 0.f};

  short8 gfrag;
  if (producer)
    gfrag = *(const short8*)&gtb[(size_t)(mtile + pidx * 16 + li) * KD + q * 8];

  f32x4 acc[8][2];  // [ms][cs] : D[m=ms*16+q*4+reg][c=c0+cs*16+li]
#pragma unroll
  for (int i = 0; i < 8; i++)
#pragma unroll
    for (int j = 0; j < 2; j++) acc[i][j] = zero4;

  for (int i = 0; i <= 32; i++) {
    if (producer) {
      if (i < 32) {
        const int n0 = i * 128, buf = i & 1;
        short8 af[8];
#pragma unroll
        for (int j = 0; j < 8; j++)
          af[j] = *(const short8*)&ftb[(size_t)(n0 + j * 16 + li) * KD + q * 8];
#pragma unroll
        for (int j = 0; j < 8; j++) {
          f32x4 S = MFMA16(af[j], gfrag, zero4);
          u32 p0 = pack_bf16x2(exp2f(S[0]), exp2f(S[1]));
          u32 p1 = pack_bf16x2(exp2f(S[2]), exp2f(S[3]));
          // P[m = mtile+pidx*16+li][n = j*16+q*4 .. +3] = 2^{S2[n,m]}
          *(uint2*)&Pt[buf][pidx * 16 + li][j * 16 + q * 4] = make_uint2(p0, p1);
        }
      }
    } else {
      if (i >= 1) {
        const int n0 = (i - 1) * 128, buf = (i - 1) & 1;
        short8 ah[2][2];  // rotating [kh&1][cs]; static after unroll
#pragma unroll
        for (int cs = 0; cs < 2; cs++)
          ah[0][cs] = *(const short8*)
              &hb[(size_t)(c0 + cs * 16 + li) * NDIM + n0 + q * 8];
        __builtin_amdgcn_s_setprio(1);
#pragma unroll
        for (int kh = 0; kh < 4; kh++) {
          if (kh < 3) {
#pragma unroll
            for (int cs = 0; cs < 2; cs++)
              ah[(kh + 1) & 1][cs] = *(const short8*)
                  &hb[(size_t)(c0 + cs * 16 + li) * NDIM + n0 + (kh + 1) * 32 + q * 8];
          }
#pragma unroll
          for (int half = 0; half < 2; half++) {
            short8 bm[4];
#pragma unroll
            for (int mi = 0; mi < 4; mi++) {
              const int ms = half * 4 + mi;
              bm[mi] = *(const short8*)&Pt[buf][ms * 16 + li][kh * 32 + q * 8];
            }
            __builtin_amdgcn_sched_barrier(0);  // pin the 4-read batch
#pragma unroll
            for (int mi = 0; mi < 4; mi++) {
              const int ms = half * 4 + mi;
              acc[ms][0] = MFMA16(bm[mi], ah[kh & 1][0], acc[ms][0]);
              acc[ms][1] = MFMA16(bm[mi], ah[kh & 1][1], acc[ms][1]);
            }
          }
        }
        __builtin_amdgcn_s_setprio(0);
      }
    }
    // LDS-only barrier: publish of P_i visible; consumer reads of the
    // other buffer retired; vmem (af/ah) never drained here.
    asm volatile("s_waitcnt lgkmcnt(0)" ::: "memory");
    __builtin_amdgcn_s_barrier();
  }

  // epilogue: consumers hold the full output; float4 stores (m contiguous)
  if (!producer) {
#pragma unroll
    for (int ms = 0; ms < 8; ms++) {
#pragma unroll
      for (int cs = 0; cs < 2; cs++) {
        int c = c0 + cs * 16 + li;
        int m = mtile + ms * 16 + q * 4;
        size_t idx = (size_t)c * NDIM + m;
        float4 xv = *(const float4*)&xb[idx];
        float4 o;
        o.x = gmv * acc[ms][cs][0] + xv.x;
        o.y = gmv * acc[ms][cs][1] + xv.y;
        o.z = gmv * acc[ms][cs][2] + xv.z;
        o.w = gmv * acc[ms][cs][3] + xv.w;
        *(float4*)&ob[idx] = o;
      }
    }
  }
}

// ---------------------------------------------------------------------------
extern "C" void kernel_launch(void* const* d_in, const int* in_sizes, int n_in,
                              void* d_out, int out_size, void* d_ws, size_t ws_size,
                              hipStream_t stream) {
  const float* x1 = (const float*)d_in[0];
  const float* x2 = (const float*)d_in[1];
  const float* f_w = (const float*)d_in[2];
  const float* f_b = (const float*)d_in[3];
  const float* g_w = (const float*)d_in[4];
  const float* g_b = (const float*)d_in[5];
  const float* h1_w = (const float*)d_in[6];
  const float* h1_b = (const float*)d_in[7];
  const float* h2_w = (const float*)d_in[8];
  const float* h2_b = (const float*)d_in[9];
  const float* gamma1 = (const float*)d_in[10];
  const float* gamma2 = (const float*)d_in[11];
  float* out = (float*)d_out;

  char* ws = (char*)d_ws;
  u16* xt  = (u16*)(ws);                          // [8][4096][256]  16 MB
  u16* wh  = (u16*)(ws + 16777216);               // [8][256][4096]  16 MB
  u16* ftw = (u16*)(ws + 33554432);               // [8][4096][32]    2 MB
  u16* gtw = (u16*)(ws + 35651584);               // [8][4096][32]    2 MB

  // 3-kernel pipeline (was 6): weights cast inline, L stays in LDS,
  // every grid XCD-pinned identically (bb = bid & 7).
  tfg_kernel<<<512, 256, 0, stream>>>(x1, x2, f_w, f_b, g_w, g_b,
                                      xt, ftw, gtw);

  sh_kernel<<<1024, 256, 0, stream>>>(ftw, gtw, h1_w, h2_w, h1_b, h2_b,
                                      xt, wh);

  apply_kernel<<<256, 1024, 0, stream>>>(ftw, gtw, wh, x1, x2,
                                         gamma1, gamma2, out);
}